// Round 10
// baseline (1432.510 us; speedup 1.0000x reference)
//
#include <hip/hip_runtime.h>
#include <hip/hip_bf16.h>
#include <stdint.h>

// CirculantLinear == dense GEMM: y[b,o] = sum_n x[b,n]*rows[o,n] + bias[o]
// where rows[o,n] = c[o, (4096-n) & 4095].
// M=8192, N=4096, K=4096. fp32 in/out.
// R9: i8 path (per-row symmetric quant + mfma_i32_16x16x64_i8): 140us GEMM,
//     absmax 0.047. Still serial-sum of LDS(2000cy)+MFMA(2612cy) per K-tile.
// R10: cross-block TLP: BK=64, 64KB LDS double-buffer -> 2 blocks/CU
//      (launch_bounds(512,4)). Stage-first/drain-last body (T14); while one
//      block drains its barrier, the other block's waves feed the MFMA pipe.
//      Quant kernel: c-path reverse reads vectorized (float4 + in-reg reverse).

#define B_DIM  8192
#define OUT_DIM 4096
#define IN_DIM  4096

typedef __attribute__((ext_vector_type(4))) int i32x4;

// ---- fused quantization kernel ------------------------------------------
// One block (256 thr) per row. x rows: blocks [0, B_DIM); c rows (with the
// circulant reverse-roll): blocks [B_DIM, B_DIM+OUT_DIM).

__global__ void quant_fused_kernel(const float* __restrict__ x,
                                   const float* __restrict__ c,
                                   int8_t* __restrict__ xq,
                                   int8_t* __restrict__ cq,
                                   float* __restrict__ sx,
                                   float* __restrict__ sc) {
  const int row = blockIdx.x;
  const int t = threadIdx.x;
  __shared__ float sm[4];
  float vals[16];

  if (row < B_DIM) {
    const float4* src = (const float4*)(x + (size_t)row * IN_DIM + t * 16);
#pragma unroll
    for (int j = 0; j < 4; ++j) {
      float4 v = src[j];
      vals[4 * j + 0] = v.x; vals[4 * j + 1] = v.y;
      vals[4 * j + 2] = v.z; vals[4 * j + 3] = v.w;
    }
  } else {
    const float* crow = c + (size_t)(row - B_DIM) * IN_DIM;
    const int n0 = t * 16;
    if (t == 0) {
#pragma unroll
      for (int j = 0; j < 16; ++j) vals[j] = crow[(IN_DIM - j) & (IN_DIM - 1)];
    } else {
      // s = 4096-n0-j for j=0..15: contiguous descending, no wrap for t>=1.
      const float4* src = (const float4*)(crow + (IN_DIM - n0 - 15));
      float f[16];
#pragma unroll
      for (int j = 0; j < 4; ++j) {
        float4 v = src[j];
        f[4 * j + 0] = v.x; f[4 * j + 1] = v.y;
        f[4 * j + 2] = v.z; f[4 * j + 3] = v.w;
      }
#pragma unroll
      for (int j = 0; j < 16; ++j) vals[j] = f[15 - j];
    }
  }

  float m = 0.f;
#pragma unroll
  for (int j = 0; j < 16; ++j) m = fmaxf(m, fabsf(vals[j]));
#pragma unroll
  for (int k = 32; k; k >>= 1) m = fmaxf(m, __shfl_xor(m, k));
  if ((t & 63) == 0) sm[t >> 6] = m;
  __syncthreads();
  m = fmaxf(fmaxf(sm[0], sm[1]), fmaxf(sm[2], sm[3]));

  const float inv = m > 0.f ? 127.0f / m : 0.f;
  const float scale = m * (1.0f / 127.0f);

  int4 packed;
  int* pw = (int*)&packed;
#pragma unroll
  for (int g = 0; g < 4; ++g) {
    int wbits = 0;
#pragma unroll
    for (int j = 0; j < 4; ++j) {
      float q = rintf(vals[g * 4 + j] * inv);
      q = fminf(fmaxf(q, -127.f), 127.f);
      wbits |= (((int)q) & 0xff) << (8 * j);
    }
    pw[g] = wbits;
  }

  if (row < B_DIM) {
    *(int4*)(xq + (size_t)row * IN_DIM + t * 16) = packed;
    if (t == 0) sx[row] = scale;
  } else {
    *(int4*)(cq + (size_t)(row - B_DIM) * IN_DIM + t * 16) = packed;
    if (t == 0) sc[row - B_DIM] = scale;
  }
}

// ---- GEMM ---------------------------------------------------------------

__device__ __forceinline__ void async_copy16(const void* g, void* l) {
  __builtin_amdgcn_global_load_lds(
      (const __attribute__((address_space(1))) void*)g,
      (__attribute__((address_space(3))) void*)l, 16, 0, 0);
}

// LDS: 2 buffers x 32KB: [A 256x64B | B 256x64B]. One buffer = one K-tile
// (BK=64 i8). Chunk-XOR swizzle phys_chunk = logical ^ ((row>>1)&3)
// (measured 0 conflicts); stage side applies the inverse via the per-lane
// GLOBAL source address (LDS dest stays linear for global_load_lds).

#define STAGE(BUF, koff)                                                     \
  async_copy16(sA + (koff), smem + (BUF)*32768 + w * 1024);                  \
  async_copy16(sA + (koff) + 128 * (size_t)IN_DIM,                           \
               smem + (BUF)*32768 + 8192 + w * 1024);                        \
  async_copy16(sB + (koff), smem + (BUF)*32768 + 16384 + w * 1024);          \
  async_copy16(sB + (koff) + 128 * (size_t)IN_DIM,                           \
               smem + (BUF)*32768 + 16384 + 8192 + w * 1024)

__device__ __forceinline__ void read_frags(const char* base, int aRd, int bRd,
                                           i32x4* aF, i32x4* bF) {
#pragma unroll
  for (int i = 0; i < 4; ++i)
    bF[i] = *(const i32x4*)(base + 16384 + bRd + i * 1024);
#pragma unroll
  for (int i = 0; i < 8; ++i)
    aF[i] = *(const i32x4*)(base + aRd + i * 1024);
}

__device__ __forceinline__ void mfma_tile(const i32x4* aF, const i32x4* bF,
                                          i32x4 (*acc)[4]) {
  __builtin_amdgcn_s_setprio(1);
#pragma unroll
  for (int mi = 0; mi < 8; ++mi)
#pragma unroll
    for (int ni = 0; ni < 4; ++ni)
      acc[mi][ni] = __builtin_amdgcn_mfma_i32_16x16x64_i8(
          aF[mi], bF[ni], acc[mi][ni], 0, 0, 0);
  __builtin_amdgcn_s_setprio(0);
}

#define VMC0 asm volatile("s_waitcnt vmcnt(0)" ::: "memory")
#define BAR  __builtin_amdgcn_s_barrier()

__global__ __launch_bounds__(512, 4) void gemm_kernel(
    const int8_t* __restrict__ xq,   // [8192][4096] i8
    const int8_t* __restrict__ cq,   // [4096][4096] i8 (circulant rows)
    const float* __restrict__ sx,    // [8192] row scales of x
    const float* __restrict__ sc,    // [4096] row scales of c-rows
    const float* __restrict__ bias,  // [4096]
    float* __restrict__ out) {       // [8192][4096] fp32
  __shared__ __align__(16) char smem[2 * 32768];  // 64 KiB -> 2 blocks/CU

  const int tid = threadIdx.x;
  const int w = tid >> 6, l = tid & 63;
  const int wr = w >> 2, wc = w & 3;       // 2 x 4 wave grid, wave owns 128x64

  // bijective XCD swizzle: 512 blocks = 8 XCDs x 64
  const int orig = blockIdx.x;
  const int wg = (orig & 7) * 64 + (orig >> 3);
  const int bm = (wg >> 4) * 256;
  const int bn = (wg & 15) * 256;

  // staging: phys row r = 16w + (l>>2) (+128 2nd copy); phys chunk = l&3;
  // stored logical chunk = (l&3) ^ ((l>>3)&3) -> pre-swizzled global col
  // (chunk = 16 i8).
  const int sgr = w * 16 + (l >> 2);
  const int sgc = ((l & 3) ^ ((l >> 3) & 3)) << 4;
  const int8_t* sA = xq + (size_t)(bm + sgr) * IN_DIM + sgc;
  const int8_t* sB = cq + (size_t)(bn + sgr) * IN_DIM + sgc;

  // frag reads: row = 16-aligned base + (l&15), logical chunk (l>>4)
  //   -> phys chunk = (l>>4) ^ ((l>>1)&3)
  const int swz = ((l >> 4) ^ ((l >> 1) & 3)) << 4;
  const int aRd = (wr * 128 + (l & 15)) * 64 + swz;
  const int bRd = (wc * 64 + (l & 15)) * 64 + swz;

  i32x4 acc[8][4];
#pragma unroll
  for (int i = 0; i < 8; ++i)
#pragma unroll
    for (int j = 0; j < 4; ++j) acc[i][j] = (i32x4){0, 0, 0, 0};
  i32x4 aF[8], bF[4];

  // ---- prologue: stage K-tile 0 into buf0
  STAGE(0, 0);
  VMC0; BAR;

  // ---- main loop: 2 K-tiles (BK=64) per iteration, kt = 0..61
  for (int it = 0; it < 31; ++it) {
    // kt even: stage kt+1 -> buf1 (issued FIRST: latency hides under body)
    STAGE(1, 64);
    read_frags(smem, aRd, bRd, aF, bF);
    mfma_tile(aF, bF, acc);
    VMC0; BAR;     // own stage loads long since landed; certify cross-wave
    // kt odd: stage kt+2 -> buf0
    STAGE(0, 128);
    read_frags(smem + 32768, aRd, bRd, aF, bF);
    mfma_tile(aF, bF, acc);
    VMC0; BAR;
    sA += 128; sB += 128;
  }
  // kt=62: stage kt63 -> buf1
  STAGE(1, 64);
  read_frags(smem, aRd, bRd, aF, bF);
  mfma_tile(aF, bF, acc);
  VMC0; BAR;
  // kt=63: no staging
  read_frags(smem + 32768, aRd, bRd, aF, bF);
  mfma_tile(aF, bF, acc);

  // ---- epilogue: C/D layout col=lane&15, row=(lane>>4)*4+reg
  // (dtype-independent on gfx950; i8 cell verified m121)
#pragma unroll
  for (int mi = 0; mi < 8; ++mi) {
    const int row = bm + wr * 128 + mi * 16 + (l >> 4) * 4;
    const float4 sx4 = *(const float4*)(sx + row);   // rows row..row+3
#pragma unroll
    for (int ni = 0; ni < 4; ++ni) {
      const int col = bn + wc * 64 + ni * 16 + (l & 15);
      const float scv = sc[col];
      const float bv = bias[col];
      float* po = out + (size_t)row * OUT_DIM + col;
      po[0 * (size_t)OUT_DIM] = (float)acc[mi][ni][0] * (sx4.x * scv) + bv;
      po[1 * (size_t)OUT_DIM] = (float)acc[mi][ni][1] * (sx4.y * scv) + bv;
      po[2 * (size_t)OUT_DIM] = (float)acc[mi][ni][2] * (sx4.z * scv) + bv;
      po[3 * (size_t)OUT_DIM] = (float)acc[mi][ni][3] * (sx4.w * scv) + bv;
    }
  }
}

// ---- host ---------------------------------------------------------------

extern "C" void kernel_launch(void* const* d_in, const int* in_sizes, int n_in,
                              void* d_out, int out_size, void* d_ws, size_t ws_size,
                              hipStream_t stream) {
  const float* x    = (const float*)d_in[0];
  const float* c    = (const float*)d_in[1];
  const float* bias = (const float*)d_in[2];
  float* out = (float*)d_out;

  const size_t xq_bytes = (size_t)B_DIM * IN_DIM;
  const size_t cq_bytes = (size_t)OUT_DIM * IN_DIM;
  const size_t need = xq_bytes + cq_bytes + (B_DIM + OUT_DIM) * sizeof(float);
  if (ws_size < need) return;

  int8_t* xq = (int8_t*)d_ws;
  int8_t* cq = xq + xq_bytes;
  float* sx = (float*)(cq + cq_bytes);
  float* sc = sx + B_DIM;

  quant_fused_kernel<<<B_DIM + OUT_DIM, 256, 0, stream>>>(x, c, xq, cq, sx, sc);

  const int grid = (B_DIM / 256) * (OUT_DIM / 256);  // 512
  gemm_kernel<<<grid, 512, 0, stream>>>(xq, cq, sx, sc, bias, out);
}

// Round 11
// 219.125 us; speedup vs baseline: 6.5374x; 6.5374x over previous
//
#include <hip/hip_runtime.h>
#include <hip/hip_bf16.h>
#include <stdint.h>

// CirculantLinear == dense GEMM: y[b,o] = sum_n x[b,n]*rows[o,n] + bias[o]
// where rows[o,n] = c[o, (4096-n) & 4095].
// M=8192, N=4096, K=4096. fp32 in/out.
// R9: i8 256^2 tile, 1 block/CU: GEMM 140us (serial LDS+MFMA sum).
// R10: (512,4) reg squeeze -> 128-reg cap vs 128-AGPR acc -> spill disaster.
// R11: occupancy via SMALLER ACC: 128x128 tile, 256 thr (wave owns 64x64,
//      acc=64 AGPR), launch_bounds(256,3) -> 3 blocks/CU (regs bind, no
//      spill). 2-phase stage-first loop (T14). Cross-block TLP overlaps
//      one block's barrier drain with another's MFMA (m114).

#define B_DIM  8192
#define OUT_DIM 4096
#define IN_DIM  4096

typedef __attribute__((ext_vector_type(4))) int i32x4;

// ---- fused quantization kernel ------------------------------------------

__global__ void quant_fused_kernel(const float* __restrict__ x,
                                   const float* __restrict__ c,
                                   int8_t* __restrict__ xq,
                                   int8_t* __restrict__ cq,
                                   float* __restrict__ sx,
                                   float* __restrict__ sc) {
  const int row = blockIdx.x;
  const int t = threadIdx.x;
  __shared__ float sm[4];
  float vals[16];

  if (row < B_DIM) {
    const float4* src = (const float4*)(x + (size_t)row * IN_DIM + t * 16);
#pragma unroll
    for (int j = 0; j < 4; ++j) {
      float4 v = src[j];
      vals[4 * j + 0] = v.x; vals[4 * j + 1] = v.y;
      vals[4 * j + 2] = v.z; vals[4 * j + 3] = v.w;
    }
  } else {
    const float* crow = c + (size_t)(row - B_DIM) * IN_DIM;
    const int n0 = t * 16;
    if (t == 0) {
#pragma unroll
      for (int j = 0; j < 16; ++j) vals[j] = crow[(IN_DIM - j) & (IN_DIM - 1)];
    } else {
      const float4* src = (const float4*)(crow + (IN_DIM - n0 - 15));
      float f[16];
#pragma unroll
      for (int j = 0; j < 4; ++j) {
        float4 v = src[j];
        f[4 * j + 0] = v.x; f[4 * j + 1] = v.y;
        f[4 * j + 2] = v.z; f[4 * j + 3] = v.w;
      }
#pragma unroll
      for (int j = 0; j < 16; ++j) vals[j] = f[15 - j];
    }
  }

  float m = 0.f;
#pragma unroll
  for (int j = 0; j < 16; ++j) m = fmaxf(m, fabsf(vals[j]));
#pragma unroll
  for (int k = 32; k; k >>= 1) m = fmaxf(m, __shfl_xor(m, k));
  if ((t & 63) == 0) sm[t >> 6] = m;
  __syncthreads();
  m = fmaxf(fmaxf(sm[0], sm[1]), fmaxf(sm[2], sm[3]));

  const float inv = m > 0.f ? 127.0f / m : 0.f;
  const float scale = m * (1.0f / 127.0f);

  int4 packed;
  int* pw = (int*)&packed;
#pragma unroll
  for (int g = 0; g < 4; ++g) {
    int wbits = 0;
#pragma unroll
    for (int j = 0; j < 4; ++j) {
      float q = rintf(vals[g * 4 + j] * inv);
      q = fminf(fmaxf(q, -127.f), 127.f);
      wbits |= (((int)q) & 0xff) << (8 * j);
    }
    pw[g] = wbits;
  }

  if (row < B_DIM) {
    *(int4*)(xq + (size_t)row * IN_DIM + t * 16) = packed;
    if (t == 0) sx[row] = scale;
  } else {
    *(int4*)(cq + (size_t)(row - B_DIM) * IN_DIM + t * 16) = packed;
    if (t == 0) sc[row - B_DIM] = scale;
  }
}

// ---- GEMM ---------------------------------------------------------------

__device__ __forceinline__ void async_copy16(const void* g, void* l) {
  __builtin_amdgcn_global_load_lds(
      (const __attribute__((address_space(1))) void*)g,
      (__attribute__((address_space(3))) void*)l, 16, 0, 0);
}

// LDS: 2 buffers x 16KB: [A 128x64B | B 128x64B]; one buffer = one K-tile
// (BK=64 i8). Chunk-XOR swizzle phys_chunk = logical ^ ((row>>1)&3)
// (measured 0 conflicts); stage side applies the inverse via the per-lane
// GLOBAL source address (LDS dest stays linear for global_load_lds).
// 256 threads: wave w stages rows 16w..16w+15 (+64 for the 2nd issue) of
// both A and B; row-parity term (r>>1)&3 identical for both issues.

#define STAGE(BUF, koff)                                                     \
  async_copy16(sA + (koff), smem + (BUF)*16384 + w * 1024);                  \
  async_copy16(sA + (koff) + 64 * (size_t)IN_DIM,                            \
               smem + (BUF)*16384 + 4096 + w * 1024);                        \
  async_copy16(sB + (koff), smem + (BUF)*16384 + 8192 + w * 1024);           \
  async_copy16(sB + (koff) + 64 * (size_t)IN_DIM,                            \
               smem + (BUF)*16384 + 8192 + 4096 + w * 1024)

__device__ __forceinline__ void read_frags(const char* base, int aRd, int bRd,
                                           i32x4* aF, i32x4* bF) {
#pragma unroll
  for (int i = 0; i < 4; ++i)
    bF[i] = *(const i32x4*)(base + 8192 + bRd + i * 1024);
#pragma unroll
  for (int i = 0; i < 4; ++i)
    aF[i] = *(const i32x4*)(base + aRd + i * 1024);
}

__device__ __forceinline__ void mfma_tile(const i32x4* aF, const i32x4* bF,
                                          i32x4 (*acc)[4]) {
  __builtin_amdgcn_s_setprio(1);
#pragma unroll
  for (int mi = 0; mi < 4; ++mi)
#pragma unroll
    for (int ni = 0; ni < 4; ++ni)
      acc[mi][ni] = __builtin_amdgcn_mfma_i32_16x16x64_i8(
          aF[mi], bF[ni], acc[mi][ni], 0, 0, 0);
  __builtin_amdgcn_s_setprio(0);
}

#define VMC0 asm volatile("s_waitcnt vmcnt(0)" ::: "memory")
#define BAR  __builtin_amdgcn_s_barrier()

__global__ __launch_bounds__(256, 3) void gemm_kernel(
    const int8_t* __restrict__ xq,   // [8192][4096] i8
    const int8_t* __restrict__ cq,   // [4096][4096] i8 (circulant rows)
    const float* __restrict__ sx,    // [8192] row scales of x
    const float* __restrict__ sc,    // [4096] row scales of c-rows
    const float* __restrict__ bias,  // [4096]
    float* __restrict__ out) {       // [8192][4096] fp32
  __shared__ __align__(16) char smem[2 * 16384];  // 32 KiB -> 3 blocks/CU (regs bind)

  const int tid = threadIdx.x;
  const int w = tid >> 6, l = tid & 63;
  const int wr = w >> 1, wc = w & 1;       // 2 x 2 wave grid, wave owns 64x64

  // bijective XCD swizzle: 2048 blocks = 8 XCDs x 256
  const int orig = blockIdx.x;
  const int wg = (orig & 7) * 256 + (orig >> 3);
  const int NBN = OUT_DIM / 128;           // 32
  const int bm = (wg / NBN) * 128;
  const int bn = (wg % NBN) * 128;

  // staging: phys row r = 16w + (l>>2) (+64 for 2nd issue); phys chunk = l&3;
  // stored logical chunk = (l&3) ^ ((r>>1)&3) = (l&3) ^ ((l>>3)&3).
  const int sgr = w * 16 + (l >> 2);
  const int sgc = ((l & 3) ^ ((l >> 3) & 3)) << 4;
  const int8_t* sA = xq + (size_t)(bm + sgr) * IN_DIM + sgc;
  const int8_t* sB = cq + (size_t)(bn + sgr) * IN_DIM + sgc;

  // frag reads: row = 16-aligned base + (l&15), logical chunk (l>>4)
  //   -> phys chunk = (l>>4) ^ ((l>>1)&3)
  const int swz = ((l >> 4) ^ ((l >> 1) & 3)) << 4;
  const int aRd = (wr * 64 + (l & 15)) * 64 + swz;
  const int bRd = (wc * 64 + (l & 15)) * 64 + swz;

  i32x4 acc[4][4];
#pragma unroll
  for (int i = 0; i < 4; ++i)
#pragma unroll
    for (int j = 0; j < 4; ++j) acc[i][j] = (i32x4){0, 0, 0, 0};
  i32x4 aF[4], bF[4];

  // ---- prologue: stage K-tile 0 into buf0
  STAGE(0, 0);
  VMC0; BAR;

  // ---- main loop: 2 K-tiles (BK=64) per iteration, kt = 0..61
  for (int it = 0; it < 31; ++it) {
    // kt even: stage kt+1 -> buf1 (issued first; latency hides under body)
    STAGE(1, 64);
    read_frags(smem, aRd, bRd, aF, bF);
    mfma_tile(aF, bF, acc);
    VMC0; BAR;
    // kt odd: stage kt+2 -> buf0
    STAGE(0, 128);
    read_frags(smem + 16384, aRd, bRd, aF, bF);
    mfma_tile(aF, bF, acc);
    VMC0; BAR;
    sA += 128; sB += 128;
  }
  // kt=62: stage kt63 -> buf1
  STAGE(1, 64);
  read_frags(smem, aRd, bRd, aF, bF);
  mfma_tile(aF, bF, acc);
  VMC0; BAR;
  // kt=63: no staging
  read_frags(smem + 16384, aRd, bRd, aF, bF);
  mfma_tile(aF, bF, acc);

  // ---- epilogue: C/D layout col=lane&15, row=(lane>>4)*4+reg
#pragma unroll
  for (int mi = 0; mi < 4; ++mi) {
    const int row = bm + wr * 64 + mi * 16 + (l >> 4) * 4;
    const float4 sx4 = *(const float4*)(sx + row);   // rows row..row+3
#pragma unroll
    for (int ni = 0; ni < 4; ++ni) {
      const int col = bn + wc * 64 + ni * 16 + (l & 15);
      const float scv = sc[col];
      const float bv = bias[col];
      float* po = out + (size_t)row * OUT_DIM + col;
      po[0 * (size_t)OUT_DIM] = (float)acc[mi][ni][0] * (sx4.x * scv) + bv;
      po[1 * (size_t)OUT_DIM] = (float)acc[mi][ni][1] * (sx4.y * scv) + bv;
      po[2 * (size_t)OUT_DIM] = (float)acc[mi][ni][2] * (sx4.z * scv) + bv;
      po[3 * (size_t)OUT_DIM] = (float)acc[mi][ni][3] * (sx4.w * scv) + bv;
    }
  }
}

// ---- host ---------------------------------------------------------------

extern "C" void kernel_launch(void* const* d_in, const int* in_sizes, int n_in,
                              void* d_out, int out_size, void* d_ws, size_t ws_size,
                              hipStream_t stream) {
  const float* x    = (const float*)d_in[0];
  const float* c    = (const float*)d_in[1];
  const float* bias = (const float*)d_in[2];
  float* out = (float*)d_out;

  const size_t xq_bytes = (size_t)B_DIM * IN_DIM;
  const size_t cq_bytes = (size_t)OUT_DIM * IN_DIM;
  const size_t need = xq_bytes + cq_bytes + (B_DIM + OUT_DIM) * sizeof(float);
  if (ws_size < need) return;

  int8_t* xq = (int8_t*)d_ws;
  int8_t* cq = xq + xq_bytes;
  float* sx = (float*)(cq + cq_bytes);
  float* sc = sx + B_DIM;

  quant_fused_kernel<<<B_DIM + OUT_DIM, 256, 0, stream>>>(x, c, xq, cq, sx, sc);

  const int grid = (B_DIM / 128) * (OUT_DIM / 128);  // 64*32 = 2048
  gemm_kernel<<<grid, 256, 0, stream>>>(xq, cq, sx, sc, bias, out);
}